// Round 3
// baseline (1778.422 us; speedup 1.0000x reference)
//
#include <hip/hip_runtime.h>
#include <hip/hip_bf16.h>
#include <stdint.h>

// ---------------- problem constants ----------------
constexpr int E   = 384;
constexpr int DFF = 1536;
constexpr int NH  = 6;
constexpr int HD  = 64;
constexpr int T   = 256;
constexpr int NL  = 6;
constexpr int NV  = 65;
constexpr int BB  = 128;
constexpr int MTOT = BB * T;           // 32768 rows
constexpr int CB  = 32;                // (kept for ws layout compatibility)

typedef __bf16 bf16;
typedef __attribute__((ext_vector_type(8))) __bf16 bf16x8;
typedef __attribute__((ext_vector_type(4))) __bf16 bf16x4;
typedef __attribute__((ext_vector_type(4))) float floatx4;

// LDS-only barrier: waits DS ops, leaves global loads IN FLIGHT (no vmcnt
// drain -- the r2 limiter: __syncthreads() emits s_waitcnt vmcnt(0) which
// killed the dist-2 A prefetch + B prefetch every iteration).
__device__ __forceinline__ void lds_barrier() {
    asm volatile("s_waitcnt lgkmcnt(0)" ::: "memory");
    __builtin_amdgcn_s_barrier();
}

// ---------------- generic bf16 GEMM: C = A[M,K] @ W ----------------
// v4: 512-thread blocks, 128x128 tile, GBK=64, dbuf LDS + XOR swizzle
// (conflict-free, r1-verified). Counted-vmcnt pipeline (T3/T4): raw
// s_barrier + lgkmcnt(0) only; compiler emits counted vmcnt for dataflow.
// B frags prefetched 1 iter ahead (bnext), A global prefetch 2 ahead.
// T5 setprio around MFMA cluster.
// SWAP=1: mfma(bb, af, acc) -> C^T frags: lane holds 4 consecutive cols of
// one row -> coalesced 8B bf16x4 stores. SWAP=0 (MODE5 vt): normal orient.
// MODE 0: bf16 out (+bias,+relu,N-mask) | MODE 1: bf16 residual +=
// MODE 4: f32 out + N-mask | MODE 5: fused QKV (nt<6 qk | nt>=6 vt)
#define GBM 128
#define GBN 128
#define GBK 64

template <int MODE, int SWAP>
__device__ __forceinline__ void gemm_body(
    char* AsB,
    const bf16* __restrict__ A, int lda,
    const bf16* __restrict__ Bf,
    const float* __restrict__ bias,
    void* __restrict__ Cv, void* __restrict__ Cv2, int ldc,
    int nt, int mt, int Nvalid, int K, int relu)
{
    int tid = threadIdx.x;
    int lane = tid & 63;
    int wid = tid >> 6;          // 0..7
    int wm = wid >> 2, wn = wid & 3;
    int lq = lane >> 4, lr = lane & 15;

    const bf16* Ab = A + (long)mt * GBM * lda;

    // ---- A staging: thread covers rows srow, srow+64; 8 k-elems ----
    int srow = tid >> 3;            // 0..63
    int skc  = (tid & 7) * 8;       // k element offset 0..56
    const bf16* Arow = Ab + (long)srow * lda + skc;
    const long a2 = 64 * (long)lda;

    // swizzled write: 16B slot = (tid&7) ^ (srow&7)
    int wcol = ((tid & 7) * 16) ^ ((srow & 7) << 4);
    char* wp0 = AsB + srow * 128 + wcol;     // +8192 for row+64, +16384 buf

    int nk = K / GBK;
    int nks = K / 32;
    // B fragment base: c16base = nt*8 + wn*2
    const bf16* Bq = Bf + ((long)(nt * 8 + wn * 2) * nks) * 512 + lane * 8;

    floatx4 zero = {0.f, 0.f, 0.f, 0.f};
    floatx4 acc[4][2];
#pragma unroll
    for (int i = 0; i < 4; i++)
#pragma unroll
        for (int j = 0; j < 2; j++) acc[i][j] = zero;

    // read-side frag base: row = wm*64 + mi*16 + lr
    const char* rp0 = AsB + (wm * 64 + lr) * 128;
    int rx0 = (lq * 16) ^ ((lr & 7) << 4);    // kh=0; kh=1 is rx0^64

    // ---- prologue: tile0 -> regs -> buf0; tile1 -> regs; B(0) -> bb ----
    bf16x8 ra[2];
    ra[0] = *(const bf16x8*)(Arow);
    ra[1] = *(const bf16x8*)(Arow + a2);
    *(bf16x8*)(wp0)        = ra[0];
    *(bf16x8*)(wp0 + 8192) = ra[1];
    if (nk > 1) {
        ra[0] = *(const bf16x8*)(Arow + GBK);
        ra[1] = *(const bf16x8*)(Arow + a2 + GBK);
    }
    bf16x8 bb[4];
#pragma unroll
    for (int ni = 0; ni < 2; ni++)
#pragma unroll
        for (int kh = 0; kh < 2; kh++)
            bb[ni * 2 + kh] = *(const bf16x8*)(Bq + ((long)ni * nks + kh) * 512);
    lds_barrier();

    for (int ki = 0; ki < nk; ki++) {
        int ib = ki & 1;
        // B prefetch for NEXT iter (in flight across the barrier)
        bf16x8 bnext[4];
        if (ki + 1 < nk) {
#pragma unroll
            for (int ni = 0; ni < 2; ni++)
#pragma unroll
                for (int kh = 0; kh < 2; kh++)
                    bnext[ni * 2 + kh] =
                        *(const bf16x8*)(Bq + ((long)ni * nks + 2 * (ki + 1) + kh) * 512);
        }
        // stage next A tile (regs -> LDS other buffer)
        if (ki + 1 < nk) {
            char* wp = wp0 + (1 - ib) * 16384;
            *(bf16x8*)(wp)        = ra[0];
            *(bf16x8*)(wp + 8192) = ra[1];
        }
        // dist-2 A global prefetch (stays in flight across barriers)
        if (ki + 2 < nk) {
            long koff = (long)(ki + 2) * GBK;
            ra[0] = *(const bf16x8*)(Arow + koff);
            ra[1] = *(const bf16x8*)(Arow + a2 + koff);
        }
        const char* rp = rp0 + ib * 16384;

        bf16x8 af[4];
#pragma unroll
        for (int mi = 0; mi < 4; mi++)
            af[mi] = *(const bf16x8*)(rp + mi * 2048 + rx0);
        __builtin_amdgcn_s_setprio(1);
#pragma unroll
        for (int mi = 0; mi < 4; mi++)
#pragma unroll
            for (int ni = 0; ni < 2; ni++)
                acc[mi][ni] = SWAP
                    ? __builtin_amdgcn_mfma_f32_16x16x32_bf16(bb[ni * 2], af[mi], acc[mi][ni], 0, 0, 0)
                    : __builtin_amdgcn_mfma_f32_16x16x32_bf16(af[mi], bb[ni * 2], acc[mi][ni], 0, 0, 0);
        __builtin_amdgcn_s_setprio(0);
#pragma unroll
        for (int mi = 0; mi < 4; mi++)
            af[mi] = *(const bf16x8*)(rp + mi * 2048 + (rx0 ^ 64));
        __builtin_amdgcn_s_setprio(1);
#pragma unroll
        for (int mi = 0; mi < 4; mi++)
#pragma unroll
            for (int ni = 0; ni < 2; ni++)
                acc[mi][ni] = SWAP
                    ? __builtin_amdgcn_mfma_f32_16x16x32_bf16(bb[ni * 2 + 1], af[mi], acc[mi][ni], 0, 0, 0)
                    : __builtin_amdgcn_mfma_f32_16x16x32_bf16(af[mi], bb[ni * 2 + 1], acc[mi][ni], 0, 0, 0);
        __builtin_amdgcn_s_setprio(0);
#pragma unroll
        for (int i = 0; i < 4; i++) bb[i] = bnext[i];
        // LDS-only barrier: ds_write/ds_read of this iter complete; global
        // prefetches (bnext, ra) remain outstanding -> counted vmcnt at use.
        lds_barrier();
    }

    int m0 = mt * GBM, n0 = nt * GBN;
#pragma unroll
    for (int mi = 0; mi < 4; mi++) {
#pragma unroll
        for (int ni = 0; ni < 2; ni++) {
            floatx4 v = acc[mi][ni];
            if (SWAP) {
                // lane holds row rowL, cols col0..col0+3
                int rowL = m0 + wm * 64 + mi * 16 + lr;
                int col0 = n0 + wn * 32 + ni * 16 + lq * 4;
                if (MODE == 5) {
                    bf16x4 pv;
#pragma unroll
                    for (int r = 0; r < 4; r++) pv[r] = (bf16)(v[r] + bias[col0 + r]);
                    *(bf16x4*)((bf16*)Cv + (long)rowL * 768 + col0) = pv;
                } else if (MODE == 1) {
                    bf16* Cp = (bf16*)Cv;
                    bf16x4* ptr = (bf16x4*)(Cp + (long)rowL * ldc + col0);
                    bf16x4 old = *ptr;
                    bf16x4 pv;
#pragma unroll
                    for (int r = 0; r < 4; r++)
                        pv[r] = (bf16)((float)old[r] + v[r] + bias[col0 + r]);
                    *ptr = pv;
                } else if (MODE == 4) {
                    float* Cp = (float*)Cv;
#pragma unroll
                    for (int r = 0; r < 4; r++)
                        if (col0 + r < Nvalid)
                            Cp[(long)rowL * ldc + col0 + r] = v[r] + bias[col0 + r];
                } else {
                    if (col0 < Nvalid) {
                        bf16x4 pv;
#pragma unroll
                        for (int r = 0; r < 4; r++) {
                            float x = v[r] + (bias ? bias[col0 + r] : 0.f);
                            if (relu) x = fmaxf(x, 0.f);
                            pv[r] = (bf16)x;
                        }
                        *(bf16x4*)((bf16*)Cv + (long)rowL * ldc + col0) = pv;
                    }
                }
            } else {
                // MODE 5 vt blocks: lane holds col colL, rows row0..row0+3
                int row0 = m0 + wm * 64 + mi * 16 + lq * 4;
                int colL = n0 + wn * 32 + ni * 16 + lr;   // 768..1151
                float bv = bias[colL];
                bf16x4 pv;
#pragma unroll
                for (int r = 0; r < 4; r++) pv[r] = (bf16)(v[r] + bv);
                int bidx = row0 >> 8, pos = row0 & 255, e = colL - 768;
                *(bf16x4*)((bf16*)Cv2 + (long)bidx * (E * T) + (long)e * T + pos) = pv;
            }
        }
    }
}

template <int MODE>
__global__ __launch_bounds__(512, 4) void k_gemm(
    const bf16* __restrict__ A, int lda,
    const bf16* __restrict__ Bf,
    const float* __restrict__ bias,
    void* __restrict__ Cv, void* __restrict__ Cv2, int ldc,
    int Mtiles, int Ntiles, int Nvalid, int K,
    int relu)
{
    __shared__ __align__(16) char AsB[2 * 16384];

    // XCD swizzle: all N-tiles of an M-tile land on one XCD's L2.
    int nb = gridDim.x;
    int per = nb >> 3;
    int bphys = blockIdx.x;
    int bid = (bphys & 7) * per + (bphys >> 3);

    int nt = bid % Ntiles;
    int mt = bid / Ntiles;

    if (MODE == 5 && nt >= 6)
        gemm_body<5, 0>(AsB, A, lda, Bf, bias, Cv, Cv2, ldc, nt, mt, Nvalid, K, relu);
    else
        gemm_body<MODE, 1>(AsB, A, lda, Bf, bias, Cv, Cv2, ldc, nt, mt, Nvalid, K, relu);
}

// ---------------- fused causal attention (LDS-staged K/V) ----------------
__global__ __launch_bounds__(256) void k_attn(
    const bf16* __restrict__ qk, const bf16* __restrict__ vt,
    bf16* __restrict__ o)
{
    int nb = gridDim.x;
    int per = nb >> 3;
    int bphys = blockIdx.x;
    int bid = (bphys & 7) * per + (bphys >> 3);

    int qt = bid & 3; bid >>= 2;
    int h = bid % NH; int b = bid / NH;
    int tid = threadIdx.x;
    int lane = tid & 63;
    int w = tid >> 6;
    int lq = lane >> 4;     // 0..3
    int lr = lane & 15;

    __shared__ __align__(16) bf16 Ks[256 * 72];   // K rows padded; reused for P
    __shared__ __align__(16) bf16 Vs[64 * 264];   // V^T rows padded

    const bf16* qbase = qk + (long)(b * T + qt * 64 + w * 16) * 768 + h * 64;
    const bf16* kbase = qk + (long)(b * T) * 768 + 384 + h * 64;
    const bf16* vbase = vt + ((long)b * E + h * 64) * T;

#pragma unroll
    for (int i = 0; i < 8; i++) {
        int idx = i * 256 + tid;
        int row = idx >> 3, off = (idx & 7) * 8;
        *(bf16x8*)(&Ks[row * 72 + off]) = *(const bf16x8*)(kbase + (long)row * 768 + off);
    }
#pragma unroll
    for (int i = 0; i < 8; i++) {
        int idx = i * 256 + tid;
        int row = idx >> 5, off = (idx & 31) * 8;
        *(bf16x8*)(&Vs[row * 264 + off]) = *(const bf16x8*)(vbase + (long)row * 256 + off);
    }

    bf16x8 aq0 = *(const bf16x8*)(qbase + (long)lr * 768 + lq * 8);
    bf16x8 aq1 = *(const bf16x8*)(qbase + (long)lr * 768 + 32 + lq * 8);

    __syncthreads();

    const int ntmax = qt * 4 + 3;
    floatx4 zero = {0.f, 0.f, 0.f, 0.f};
    floatx4 s[16];
#pragma unroll
    for (int nt = 0; nt < 16; nt++) s[nt] = zero;

#pragma unroll
    for (int nt = 0; nt < 16; nt++) {
        if (nt <= ntmax) {
            const bf16* kp = &Ks[(nt * 16 + lr) * 72 + lq * 8];
            bf16x8 b0 = *(const bf16x8*)(kp);
            bf16x8 b1 = *(const bf16x8*)(kp + 32);
            s[nt] = __builtin_amdgcn_mfma_f32_16x16x32_bf16(aq0, b0, s[nt], 0, 0, 0);
            s[nt] = __builtin_amdgcn_mfma_f32_16x16x32_bf16(aq1, b1, s[nt], 0, 0, 0);
        }
    }

    int trow0 = qt * 64 + w * 16 + lq * 4;
    float m4[4] = {-3e38f, -3e38f, -3e38f, -3e38f};
#pragma unroll
    for (int nt = 0; nt < 16; nt++) {
        if (nt <= ntmax) {
            int tc = nt * 16 + lr;
#pragma unroll
            for (int r = 0; r < 4; r++) {
                float v = s[nt][r] * 0.125f;
                if (tc > trow0 + r) v = -3e38f;
                s[nt][r] = v;
                m4[r] = fmaxf(m4[r], v);
            }
        }
    }
#pragma unroll
    for (int r = 0; r < 4; r++) {
#pragma unroll
        for (int off = 1; off < 16; off <<= 1)
            m4[r] = fmaxf(m4[r], __shfl_xor(m4[r], off, 64));
    }

    float l4[4] = {0.f, 0.f, 0.f, 0.f};
#pragma unroll
    for (int nt = 0; nt < 16; nt++) {
        if (nt <= ntmax) {
#pragma unroll
            for (int r = 0; r < 4; r++) {
                float pv = __expf(s[nt][r] - m4[r]);
                l4[r] += pv;
                s[nt][r] = pv;
            }
        }
    }
#pragma unroll
    for (int r = 0; r < 4; r++) {
#pragma unroll
        for (int off = 1; off < 16; off <<= 1)
            l4[r] += __shfl_xor(l4[r], off, 64);
    }

    __syncthreads();   // Ks fully consumed -> reuse for P

    bf16* P = Ks + w * (16 * 264);
#pragma unroll
    for (int nt = 0; nt < 16; nt++) {
        if (nt <= ntmax) {
#pragma unroll
            for (int r = 0; r < 4; r++)
                P[(lq * 4 + r) * 264 + nt * 16 + lr] = (bf16)s[nt][r];
        }
    }

    floatx4 oacc[4];
#pragma unroll
    for (int nd = 0; nd < 4; nd++) oacc[nd] = zero;
    const int kkmax = 2 * (qt + 1);
#pragma unroll
    for (int kk = 0; kk < 8; kk++) {
        if (kk < kkmax) {
            bf16x8 ap = *(const bf16x8*)(&P[lr * 264 + kk * 32 + lq * 8]);
#pragma unroll
            for (int nd = 0; nd < 4; nd++) {
                bf16x8 bv = *(const bf16x8*)(&Vs[(nd * 16 + lr) * 264 + kk * 32 + lq * 8]);
                oacc[nd] = __builtin_amdgcn_mfma_f32_16x16x32_bf16(ap, bv, oacc[nd], 0, 0, 0);
            }
        }
    }

#pragma unroll
    for (int r = 0; r < 4; r++) {
        float inv = 1.0f / l4[r];
        long rowg = (long)b * T + trow0 + r;
#pragma unroll
        for (int nd = 0; nd < 4; nd++) {
            o[rowg * E + h * 64 + nd * 16 + lr] = (bf16)(oacc[nd][r] * inv);
        }
    }
}

// ---------------- layernorm: bf16 in -> bf16 out (wave per row) ----------------
__global__ void k_ln(const bf16* __restrict__ x, const float* __restrict__ g,
                     const float* __restrict__ b, bf16* __restrict__ h) {
    int row = blockIdx.x * 4 + (threadIdx.x >> 6);
    int lane = threadIdx.x & 63;
    const bf16* xr = x + (long)row * E;
    float v[6];
    float s = 0.f;
#pragma unroll
    for (int i = 0; i < 6; i++) { v[i] = (float)xr[lane + 64 * i]; s += v[i]; }
#pragma unroll
    for (int o = 1; o < 64; o <<= 1) s += __shfl_xor(s, o, 64);
    float mu = s * (1.0f / E);
    float q = 0.f;
#pragma unroll
    for (int i = 0; i < 6; i++) { float d = v[i] - mu; q += d * d; }
#pragma unroll
    for (int o = 1; o < 64; o <<= 1) q += __shfl_xor(q, o, 64);
    float rs = rsqrtf(q * (1.0f / E) + 1e-5f);
    bf16* hr = h + (long)row * E;
#pragma unroll
    for (int i = 0; i < 6; i++) {
        int c = lane + 64 * i;
        hr[c] = (bf16)((v[i] - mu) * rs * g[c] + b[c]);
    }
}

// ---------------- fragment-layout weight transpose ----------------
// W [L][K][N] (f32) -> Wf [L][NPAD/16][K/32][64][8] (bf16), cols>=N zero.
// Wf[((c16*nks + ks)*64 + lane)*8 + j] = W[ks*32 + (lane>>4)*8 + j][c16*16 + (lane&15)]
__global__ void k_transpose_frag(const float* __restrict__ W, bf16* __restrict__ Wf,
                                 int K, int N, int NPAD) {
    long idx = (long)blockIdx.x * 256 + threadIdx.x;   // over NL*NPAD*K
    long per = (long)NPAD * K;
    int l = (int)(idx / per);
    long r = idx - (long)l * per;
    int j = (int)(r & 7); r >>= 3;
    int lane = (int)(r & 63); r >>= 6;
    int nks = K / 32;
    int ks = (int)(r % nks);
    int c16 = (int)(r / nks);
    int col = c16 * 16 + (lane & 15);
    int k = ks * 32 + (lane >> 4) * 8 + j;
    Wf[idx] = (col < N) ? (bf16)W[((long)l * K + k) * N + col] : (bf16)0.0f;
}

// ---------------- fragment-layout fused QKV transpose: [L] cols 0..1151 ----------------
__global__ void k_transpose_qkv_frag(const float* __restrict__ Wq, const float* __restrict__ Wk,
                                     const float* __restrict__ Wv, bf16* __restrict__ Wf) {
    long idx = (long)blockIdx.x * 256 + threadIdx.x;   // over NL*1152*384
    long per = (long)1152 * E;
    int l = (int)(idx / per);
    long r = idx - (long)l * per;
    int j = (int)(r & 7); r >>= 3;
    int lane = (int)(r & 63); r >>= 6;
    int nks = E / 32;                                   // 12
    int ks = (int)(r % nks);
    int c16 = (int)(r / nks);
    int col = c16 * 16 + (lane & 15);                   // 0..1151
    int k = ks * 32 + (lane >> 4) * 8 + j;
    const float* src;
    int cc;
    if (col < 384)      { src = Wq; cc = col; }
    else if (col < 768) { src = Wk; cc = col - 384; }
    else                { src = Wv; cc = col - 768; }
    Wf[idx] = (bf16)src[((long)l * E + k) * E + cc];
}

// ---------------- fused QKV bias concat: [L][1152] f32 ----------------
__global__ void k_bias_qkv(const float* __restrict__ bq, const float* __restrict__ bk,
                           const float* __restrict__ bv, float* __restrict__ bqkv) {
    int idx = blockIdx.x * 256 + threadIdx.x;
    int l = idx / 1152;
    int j = idx - l * 1152;
    const float* src;
    int jj;
    if (j < 384)      { src = bq; jj = j; }
    else if (j < 768) { src = bk; jj = j - 384; }
    else              { src = bv; jj = j - 768; }
    bqkv[idx] = src[l * E + jj];
}

// ---------------- embedding + positional -> bf16 residual ----------------
__global__ void k_embed(const int* __restrict__ tokens, const float* __restrict__ pos,
                        const float* __restrict__ emb, bf16* __restrict__ x) {
    long idx = (long)blockIdx.x * 256 + threadIdx.x;
    int e = (int)(idx % E);
    long bt = idx / E;
    int t = (int)(bt % T);
    int tok = tokens[bt];
    x[idx] = (bf16)(emb[(long)tok * E + e] + pos[(long)t * E + e]);
}

// ---------------- launcher ----------------
extern "C" void kernel_launch(void* const* d_in, const int* in_sizes, int n_in,
                              void* d_out, int out_size, void* d_ws, size_t ws_size,
                              hipStream_t stream) {
    const int*   tokens = (const int*)d_in[0];
    const float* pos  = (const float*)d_in[1];
    const float* emb  = (const float*)d_in[2];
    const float* Wq   = (const float*)d_in[3];
    const float* bq   = (const float*)d_in[4];
    const float* Wk   = (const float*)d_in[5];
    const float* bk   = (const float*)d_in[6];
    const float* Wv   = (const float*)d_in[7];
    const float* bv   = (const float*)d_in[8];
    const float* Wo   = (const float*)d_in[9];
    const float* bo   = (const float*)d_in[10];
    const float* g1   = (const float*)d_in[11];
    const float* be1  = (const float*)d_in[12];
    const float* W1   = (const float*)d_in[13];
    const float* c1   = (const float*)d_in[14];
    const float* W2   = (const float*)d_in[15];
    const float* c2   = (const float*)d_in[16];
    const float* g2   = (const float*)d_in[17];
    const float* be2  = (const float*)d_in[18];
    const float* Wl   = (const float*)d_in[19];
    const float* bl   = (const float*)d_in[20];

    // ---- workspace layout (~173 MB peak) ----
    char* p = (char*)d_ws;
    bf16* x  = (bf16*)p;   p += (long)MTOT * E * 2;          // residual (bf16)
    bf16* h  = (bf16*)p;   p += (long)MTOT * E * 2;          // LN out / o (alias)
    bf16* qk = (bf16*)p;   p += (long)MTOT * 768 * 2;        // fused Q|K
    bf16* vt = (bf16*)p;   p += (long)BB * E * T * 2;        // V^T per (seq,head)
    bf16* SP = (bf16*)p;   p += (long)CB * NH * T * T * 2;   // kept only for mid alias span
    bf16* WqkvF = (bf16*)p; p += (long)NL * 1152 * E * 2;    // fragment layouts
    bf16* WoF = (bf16*)p;  p += (long)NL * E * E * 2;
    bf16* W1F = (bf16*)p;  p += (long)NL * DFF * E * 2;
    bf16* W2F = (bf16*)p;  p += (long)NL * E * DFF * 2;
    bf16* WlF = (bf16*)p;  p += (long)128 * E * 2;
    float* bqkv = (float*)p; p += (long)NL * 1152 * 4;
    bf16* mid = qk;          // alias: qk+vt+SP = 100.66 MB = MTOT*DFF*2 exactly
    bf16* o   = h;
    (void)SP;

    // ---- setup (once per call) ----
    k_transpose_qkv_frag<<<(NL * 1152 * E) / 256, 256, 0, stream>>>(Wq, Wk, Wv, WqkvF);
    k_transpose_frag<<<(NL * E * E) / 256, 256, 0, stream>>>(Wo, WoF, E, E, E);
    k_transpose_frag<<<(NL * DFF * E) / 256, 256, 0, stream>>>(W1, W1F, E, DFF, DFF);
    k_transpose_frag<<<(NL * E * DFF) / 256, 256, 0, stream>>>(W2, W2F, DFF, E, E);
    k_transpose_frag<<<(128 * E) / 256, 256, 0, stream>>>(Wl, WlF, E, NV, 128);
    k_bias_qkv<<<(NL * 1152) / 256, 256, 0, stream>>>(bq, bk, bv, bqkv);

    // ---- embedding ----
    k_embed<<<(MTOT * E) / 256, 256, 0, stream>>>(tokens, pos, emb, x);

    for (int l = 0; l < NL; l++) {
        // LN1
        k_ln<<<MTOT / 4, 256, 0, stream>>>(x, g1 + l * E, be1 + l * E, h);
        // fused QKV: M=32768, N=1152, K=384
        k_gemm<5><<<256 * 9, 512, 0, stream>>>(h, E, WqkvF + (long)l * 1152 * E,
                                               bqkv + l * 1152, qk, vt, 0,
                                               256, 9, 1152, E, 0);
        // fused causal attention
        k_attn<<<BB * NH * 4, 256, 0, stream>>>(qk, vt, o);
        // x += O @ Wo + bo
        k_gemm<1><<<256 * 3, 512, 0, stream>>>(o, E, WoF + (long)l * E * E,
                                               bo + l * E, x, nullptr, E,
                                               256, 3, E, E, 0);
        // LN2
        k_ln<<<MTOT / 4, 256, 0, stream>>>(x, g2 + l * E, be2 + l * E, h);
        // mid = relu(h @ W1 + c1)
        k_gemm<0><<<256 * 12, 512, 0, stream>>>(h, E, W1F + (long)l * DFF * E,
                                                c1 + l * DFF, mid, nullptr, DFF,
                                                256, 12, DFF, E, 1);
        // x += mid @ W2 + c2
        k_gemm<1><<<256 * 3, 512, 0, stream>>>(mid, DFF, W2F + (long)l * E * DFF,
                                               c2 + l * E, x, nullptr, E,
                                               256, 3, E, DFF, 0);
    }

    // logits = x @ Wl + bl  (N=65 masked from 128), f32 out
    k_gemm<4><<<256 * 1, 512, 0, stream>>>(x, E, WlF,
                                           bl, d_out, nullptr, NV,
                                           256, 1, NV, E, 0);
}

// Round 4
// 1676.406 us; speedup vs baseline: 1.0609x; 1.0609x over previous
//
#include <hip/hip_runtime.h>
#include <hip/hip_bf16.h>
#include <stdint.h>

// ---------------- problem constants ----------------
constexpr int E   = 384;
constexpr int DFF = 1536;
constexpr int NH  = 6;
constexpr int HD  = 64;
constexpr int T   = 256;
constexpr int NL  = 6;
constexpr int NV  = 65;
constexpr int BB  = 128;
constexpr int MTOT = BB * T;           // 32768 rows
constexpr int CB  = 32;                // (kept for ws layout compatibility)

typedef __bf16 bf16;
typedef __attribute__((ext_vector_type(8))) __bf16 bf16x8;
typedef __attribute__((ext_vector_type(4))) __bf16 bf16x4;
typedef __attribute__((ext_vector_type(4))) float floatx4;

// direct global->LDS DMA, 16B per lane (dest = wave-uniform base + lane*16)
__device__ __forceinline__ void gload_lds16(const void* g, void* l) {
    __builtin_amdgcn_global_load_lds(
        (const __attribute__((address_space(1))) void*)g,
        (__attribute__((address_space(3))) void*)l, 16, 0, 0);
}

// ---------------- generic bf16 GEMM: C = A[M,K] @ W ----------------
// v5: 512-thread blocks, 128x128 tile, GBK=64, dbuf LDS.
// A staged via global_load_lds (16B DMA): LDS dest LINEAR, XOR swizzle moved
// to the per-lane GLOBAL source (slot s reads k-chunk s^(row&7); permutation
// stays inside the 128B row -> still fully coalesced). Read-side swizzle
// unchanged (conflict-free, r1-verified 0 conflicts). No reg round-trip:
// frees ~10 VGPR -> total ~80 regs -> __launch_bounds__(512,6) = 3 blocks/CU
// (r3 was quantized to 2 blocks at 84 regs -> 38% occupancy, latency-bound).
// __syncthreads' vmcnt(0)+lgkmcnt(0) drain is exactly the DMA-completion wait
// (B frags are issued BEFORE the DMA and consumed in-iter -> counted waits).
// SWAP=1: mfma(bb, af, acc) -> C^T frags: lane holds 4 consecutive cols of
// one row -> coalesced 8B bf16x4 stores. SWAP=0 (MODE5 vt): normal orient.
// MODE 0: bf16 out (+bias,+relu,N-mask) | MODE 1: bf16 residual +=
// MODE 4: f32 out + N-mask | MODE 5: fused QKV (nt<6 qk | nt>=6 vt)
#define GBM 128
#define GBN 128
#define GBK 64

template <int MODE, int SWAP>
__device__ __forceinline__ void gemm_body(
    char* AsB,
    const bf16* __restrict__ A, int lda,
    const bf16* __restrict__ Bf,
    const float* __restrict__ bias,
    void* __restrict__ Cv, void* __restrict__ Cv2, int ldc,
    int nt, int mt, int Nvalid, int K, int relu)
{
    int tid = threadIdx.x;
    int lane = tid & 63;
    int wid = tid >> 6;          // 0..7
    int wm = wid >> 2, wn = wid & 3;
    int lq = lane >> 4, lr = lane & 15;

    const bf16* Ab = A + (long)mt * GBM * lda;

    // ---- A staging map (DMA): thread = (srow 0..63, slot 0..7) ----
    // LDS linear: row r, 16B slot s at offset r*128 + s*16  (rows 64..127 at +8192)
    // source pre-swizzle: slot s takes k-chunk c = s ^ (srow&7)
    int srow = tid >> 3;
    int slot = tid & 7;
    int skc  = (slot ^ (srow & 7)) * 8;          // k element offset (swizzled)
    const bf16* Arow = Ab + (long)srow * lda + skc;
    const long a2 = 64 * (long)lda;
    int wofs = wid * 1024;                       // wave-uniform LDS base

    int nk = K / GBK;
    int nks = K / 32;
    // B fragment base: c16base = nt*8 + wn*2
    const bf16* Bq = Bf + ((long)(nt * 8 + wn * 2) * nks) * 512 + lane * 8;

    floatx4 zero = {0.f, 0.f, 0.f, 0.f};
    floatx4 acc[4][2];
#pragma unroll
    for (int i = 0; i < 4; i++)
#pragma unroll
        for (int j = 0; j < 2; j++) acc[i][j] = zero;

    // read-side frag base: row = wm*64 + mi*16 + lr
    const char* rp0 = AsB + (wm * 64 + lr) * 128;
    int rx0 = (lq * 16) ^ ((lr & 7) << 4);       // kh=0; kh=1 is rx0^64

    // ---- prologue: DMA tile0 -> buf0 ----
    {
        char* base = AsB + wofs;
        gload_lds16(Arow,      base);
        gload_lds16(Arow + a2, base + 8192);
    }
    asm volatile("s_waitcnt vmcnt(0)" ::: "memory");
    __syncthreads();

    for (int ki = 0; ki < nk; ki++) {
        int ib = ki & 1;
        // B frags for THIS iter (issued before the DMA so their counted
        // vmcnt waits don't force the DMA to drain)
        bf16x8 bb[4];
#pragma unroll
        for (int ni = 0; ni < 2; ni++)
#pragma unroll
            for (int kh = 0; kh < 2; kh++)
                bb[ni * 2 + kh] =
                    *(const bf16x8*)(Bq + ((long)ni * nks + 2 * ki + kh) * 512);
        // DMA next A tile into the other buffer (lands by iter-end barrier)
        if (ki + 1 < nk) {
            long koff = (long)(ki + 1) * GBK;
            char* base = AsB + (1 - ib) * 16384 + wofs;
            gload_lds16(Arow + koff,      base);
            gload_lds16(Arow + a2 + koff, base + 8192);
        }
        const char* rp = rp0 + ib * 16384;

        bf16x8 af[4];
#pragma unroll
        for (int mi = 0; mi < 4; mi++)
            af[mi] = *(const bf16x8*)(rp + mi * 2048 + rx0);
#pragma unroll
        for (int mi = 0; mi < 4; mi++)
#pragma unroll
            for (int ni = 0; ni < 2; ni++)
                acc[mi][ni] = SWAP
                    ? __builtin_amdgcn_mfma_f32_16x16x32_bf16(bb[ni * 2], af[mi], acc[mi][ni], 0, 0, 0)
                    : __builtin_amdgcn_mfma_f32_16x16x32_bf16(af[mi], bb[ni * 2], acc[mi][ni], 0, 0, 0);
#pragma unroll
        for (int mi = 0; mi < 4; mi++)
            af[mi] = *(const bf16x8*)(rp + mi * 2048 + (rx0 ^ 64));
#pragma unroll
        for (int mi = 0; mi < 4; mi++)
#pragma unroll
            for (int ni = 0; ni < 2; ni++)
                acc[mi][ni] = SWAP
                    ? __builtin_amdgcn_mfma_f32_16x16x32_bf16(bb[ni * 2 + 1], af[mi], acc[mi][ni], 0, 0, 0)
                    : __builtin_amdgcn_mfma_f32_16x16x32_bf16(af[mi], bb[ni * 2 + 1], acc[mi][ni], 0, 0, 0);
        // barrier drain (vmcnt0) completes the next-tile DMA; nothing else
        // is outstanding here, so the full drain is free.
        __syncthreads();
    }

    int m0 = mt * GBM, n0 = nt * GBN;
#pragma unroll
    for (int mi = 0; mi < 4; mi++) {
#pragma unroll
        for (int ni = 0; ni < 2; ni++) {
            floatx4 v = acc[mi][ni];
            if (SWAP) {
                // lane holds row rowL, cols col0..col0+3
                int rowL = m0 + wm * 64 + mi * 16 + lr;
                int col0 = n0 + wn * 32 + ni * 16 + lq * 4;
                if (MODE == 5) {
                    bf16x4 pv;
#pragma unroll
                    for (int r = 0; r < 4; r++) pv[r] = (bf16)(v[r] + bias[col0 + r]);
                    *(bf16x4*)((bf16*)Cv + (long)rowL * 768 + col0) = pv;
                } else if (MODE == 1) {
                    bf16* Cp = (bf16*)Cv;
                    bf16x4* ptr = (bf16x4*)(Cp + (long)rowL * ldc + col0);
                    bf16x4 old = *ptr;
                    bf16x4 pv;
#pragma unroll
                    for (int r = 0; r < 4; r++)
                        pv[r] = (bf16)((float)old[r] + v[r] + bias[col0 + r]);
                    *ptr = pv;
                } else if (MODE == 4) {
                    float* Cp = (float*)Cv;
#pragma unroll
                    for (int r = 0; r < 4; r++)
                        if (col0 + r < Nvalid)
                            Cp[(long)rowL * ldc + col0 + r] = v[r] + bias[col0 + r];
                } else {
                    if (col0 < Nvalid) {
                        bf16x4 pv;
#pragma unroll
                        for (int r = 0; r < 4; r++) {
                            float x = v[r] + (bias ? bias[col0 + r] : 0.f);
                            if (relu) x = fmaxf(x, 0.f);
                            pv[r] = (bf16)x;
                        }
                        *(bf16x4*)((bf16*)Cv + (long)rowL * ldc + col0) = pv;
                    }
                }
            } else {
                // MODE 5 vt blocks: lane holds col colL, rows row0..row0+3
                int row0 = m0 + wm * 64 + mi * 16 + lq * 4;
                int colL = n0 + wn * 32 + ni * 16 + lr;   // 768..1151
                float bv = bias[colL];
                bf16x4 pv;
#pragma unroll
                for (int r = 0; r < 4; r++) pv[r] = (bf16)(v[r] + bv);
                int bidx = row0 >> 8, pos = row0 & 255, e = colL - 768;
                *(bf16x4*)((bf16*)Cv2 + (long)bidx * (E * T) + (long)e * T + pos) = pv;
            }
        }
    }
}

template <int MODE>
__global__ __launch_bounds__(512, 6) void k_gemm(
    const bf16* __restrict__ A, int lda,
    const bf16* __restrict__ Bf,
    const float* __restrict__ bias,
    void* __restrict__ Cv, void* __restrict__ Cv2, int ldc,
    int Mtiles, int Ntiles, int Nvalid, int K,
    int relu)
{
    __shared__ __align__(16) char AsB[2 * 16384];

    // XCD swizzle: all N-tiles of an M-tile land on one XCD's L2.
    int nb = gridDim.x;
    int per = nb >> 3;
    int bphys = blockIdx.x;
    int bid = (bphys & 7) * per + (bphys >> 3);

    int nt = bid % Ntiles;
    int mt = bid / Ntiles;

    if (MODE == 5 && nt >= 6)
        gemm_body<5, 0>(AsB, A, lda, Bf, bias, Cv, Cv2, ldc, nt, mt, Nvalid, K, relu);
    else
        gemm_body<MODE, 1>(AsB, A, lda, Bf, bias, Cv, Cv2, ldc, nt, mt, Nvalid, K, relu);
}

// ---------------- fused causal attention (LDS-staged K/V) ----------------
__global__ __launch_bounds__(256) void k_attn(
    const bf16* __restrict__ qk, const bf16* __restrict__ vt,
    bf16* __restrict__ o)
{
    int nb = gridDim.x;
    int per = nb >> 3;
    int bphys = blockIdx.x;
    int bid = (bphys & 7) * per + (bphys >> 3);

    int qt = bid & 3; bid >>= 2;
    int h = bid % NH; int b = bid / NH;
    int tid = threadIdx.x;
    int lane = tid & 63;
    int w = tid >> 6;
    int lq = lane >> 4;     // 0..3
    int lr = lane & 15;

    __shared__ __align__(16) bf16 Ks[256 * 72];   // K rows padded; reused for P
    __shared__ __align__(16) bf16 Vs[64 * 264];   // V^T rows padded

    const bf16* qbase = qk + (long)(b * T + qt * 64 + w * 16) * 768 + h * 64;
    const bf16* kbase = qk + (long)(b * T) * 768 + 384 + h * 64;
    const bf16* vbase = vt + ((long)b * E + h * 64) * T;

#pragma unroll
    for (int i = 0; i < 8; i++) {
        int idx = i * 256 + tid;
        int row = idx >> 3, off = (idx & 7) * 8;
        *(bf16x8*)(&Ks[row * 72 + off]) = *(const bf16x8*)(kbase + (long)row * 768 + off);
    }
#pragma unroll
    for (int i = 0; i < 8; i++) {
        int idx = i * 256 + tid;
        int row = idx >> 5, off = (idx & 31) * 8;
        *(bf16x8*)(&Vs[row * 264 + off]) = *(const bf16x8*)(vbase + (long)row * 256 + off);
    }

    bf16x8 aq0 = *(const bf16x8*)(qbase + (long)lr * 768 + lq * 8);
    bf16x8 aq1 = *(const bf16x8*)(qbase + (long)lr * 768 + 32 + lq * 8);

    __syncthreads();

    const int ntmax = qt * 4 + 3;
    floatx4 zero = {0.f, 0.f, 0.f, 0.f};
    floatx4 s[16];
#pragma unroll
    for (int nt = 0; nt < 16; nt++) s[nt] = zero;

#pragma unroll
    for (int nt = 0; nt < 16; nt++) {
        if (nt <= ntmax) {
            const bf16* kp = &Ks[(nt * 16 + lr) * 72 + lq * 8];
            bf16x8 b0 = *(const bf16x8*)(kp);
            bf16x8 b1 = *(const bf16x8*)(kp + 32);
            s[nt] = __builtin_amdgcn_mfma_f32_16x16x32_bf16(aq0, b0, s[nt], 0, 0, 0);
            s[nt] = __builtin_amdgcn_mfma_f32_16x16x32_bf16(aq1, b1, s[nt], 0, 0, 0);
        }
    }

    int trow0 = qt * 64 + w * 16 + lq * 4;
    float m4[4] = {-3e38f, -3e38f, -3e38f, -3e38f};
#pragma unroll
    for (int nt = 0; nt < 16; nt++) {
        if (nt <= ntmax) {
            int tc = nt * 16 + lr;
#pragma unroll
            for (int r = 0; r < 4; r++) {
                float v = s[nt][r] * 0.125f;
                if (tc > trow0 + r) v = -3e38f;
                s[nt][r] = v;
                m4[r] = fmaxf(m4[r], v);
            }
        }
    }
#pragma unroll
    for (int r = 0; r < 4; r++) {
#pragma unroll
        for (int off = 1; off < 16; off <<= 1)
            m4[r] = fmaxf(m4[r], __shfl_xor(m4[r], off, 64));
    }

    float l4[4] = {0.f, 0.f, 0.f, 0.f};
#pragma unroll
    for (int nt = 0; nt < 16; nt++) {
        if (nt <= ntmax) {
#pragma unroll
            for (int r = 0; r < 4; r++) {
                float pv = __expf(s[nt][r] - m4[r]);
                l4[r] += pv;
                s[nt][r] = pv;
            }
        }
    }
#pragma unroll
    for (int r = 0; r < 4; r++) {
#pragma unroll
        for (int off = 1; off < 16; off <<= 1)
            l4[r] += __shfl_xor(l4[r], off, 64);
    }

    __syncthreads();   // Ks fully consumed -> reuse for P

    bf16* P = Ks + w * (16 * 264);
#pragma unroll
    for (int nt = 0; nt < 16; nt++) {
        if (nt <= ntmax) {
#pragma unroll
            for (int r = 0; r < 4; r++)
                P[(lq * 4 + r) * 264 + nt * 16 + lr] = (bf16)s[nt][r];
        }
    }

    floatx4 oacc[4];
#pragma unroll
    for (int nd = 0; nd < 4; nd++) oacc[nd] = zero;
    const int kkmax = 2 * (qt + 1);
#pragma unroll
    for (int kk = 0; kk < 8; kk++) {
        if (kk < kkmax) {
            bf16x8 ap = *(const bf16x8*)(&P[lr * 264 + kk * 32 + lq * 8]);
#pragma unroll
            for (int nd = 0; nd < 4; nd++) {
                bf16x8 bv = *(const bf16x8*)(&Vs[(nd * 16 + lr) * 264 + kk * 32 + lq * 8]);
                oacc[nd] = __builtin_amdgcn_mfma_f32_16x16x32_bf16(ap, bv, oacc[nd], 0, 0, 0);
            }
        }
    }

#pragma unroll
    for (int r = 0; r < 4; r++) {
        float inv = 1.0f / l4[r];
        long rowg = (long)b * T + trow0 + r;
#pragma unroll
        for (int nd = 0; nd < 4; nd++) {
            o[rowg * E + h * 64 + nd * 16 + lr] = (bf16)(oacc[nd][r] * inv);
        }
    }
}

// ---------------- layernorm: bf16 in -> bf16 out (wave per row) ----------------
__global__ void k_ln(const bf16* __restrict__ x, const float* __restrict__ g,
                     const float* __restrict__ b, bf16* __restrict__ h) {
    int row = blockIdx.x * 4 + (threadIdx.x >> 6);
    int lane = threadIdx.x & 63;
    const bf16* xr = x + (long)row * E;
    float v[6];
    float s = 0.f;
#pragma unroll
    for (int i = 0; i < 6; i++) { v[i] = (float)xr[lane + 64 * i]; s += v[i]; }
#pragma unroll
    for (int o = 1; o < 64; o <<= 1) s += __shfl_xor(s, o, 64);
    float mu = s * (1.0f / E);
    float q = 0.f;
#pragma unroll
    for (int i = 0; i < 6; i++) { float d = v[i] - mu; q += d * d; }
#pragma unroll
    for (int o = 1; o < 64; o <<= 1) q += __shfl_xor(q, o, 64);
    float rs = rsqrtf(q * (1.0f / E) + 1e-5f);
    bf16* hr = h + (long)row * E;
#pragma unroll
    for (int i = 0; i < 6; i++) {
        int c = lane + 64 * i;
        hr[c] = (bf16)((v[i] - mu) * rs * g[c] + b[c]);
    }
}

// ---------------- fragment-layout weight transpose ----------------
// W [L][K][N] (f32) -> Wf [L][NPAD/16][K/32][64][8] (bf16), cols>=N zero.
// Wf[((c16*nks + ks)*64 + lane)*8 + j] = W[ks*32 + (lane>>4)*8 + j][c16*16 + (lane&15)]
__global__ void k_transpose_frag(const float* __restrict__ W, bf16* __restrict__ Wf,
                                 int K, int N, int NPAD) {
    long idx = (long)blockIdx.x * 256 + threadIdx.x;   // over NL*NPAD*K
    long per = (long)NPAD * K;
    int l = (int)(idx / per);
    long r = idx - (long)l * per;
    int j = (int)(r & 7); r >>= 3;
    int lane = (int)(r & 63); r >>= 6;
    int nks = K / 32;
    int ks = (int)(r % nks);
    int c16 = (int)(r / nks);
    int col = c16 * 16 + (lane & 15);
    int k = ks * 32 + (lane >> 4) * 8 + j;
    Wf[idx] = (col < N) ? (bf16)W[((long)l * K + k) * N + col] : (bf16)0.0f;
}

// ---------------- fragment-layout fused QKV transpose: [L] cols 0..1151 ----------------
__global__ void k_transpose_qkv_frag(const float* __restrict__ Wq, const float* __restrict__ Wk,
                                     const float* __restrict__ Wv, bf16* __restrict__ Wf) {
    long idx = (long)blockIdx.x * 256 + threadIdx.x;   // over NL*1152*384
    long per = (long)1152 * E;
    int l = (int)(idx / per);
    long r = idx - (long)l * per;
    int j = (int)(r & 7); r >>= 3;
    int lane = (int)(r & 63); r >>= 6;
    int nks = E / 32;                                   // 12
    int ks = (int)(r % nks);
    int c16 = (int)(r / nks);
    int col = c16 * 16 + (lane & 15);                   // 0..1151
    int k = ks * 32 + (lane >> 4) * 8 + j;
    const float* src;
    int cc;
    if (col < 384)      { src = Wq; cc = col; }
    else if (col < 768) { src = Wk; cc = col - 384; }
    else                { src = Wv; cc = col - 768; }
    Wf[idx] = (bf16)src[((long)l * E + k) * E + cc];
}

// ---------------- fused QKV bias concat: [L][1152] f32 ----------------
__global__ void k_bias_qkv(const float* __restrict__ bq, const float* __restrict__ bk,
                           const float* __restrict__ bv, float* __restrict__ bqkv) {
    int idx = blockIdx.x * 256 + threadIdx.x;
    int l = idx / 1152;
    int j = idx - l * 1152;
    const float* src;
    int jj;
    if (j < 384)      { src = bq; jj = j; }
    else if (j < 768) { src = bk; jj = j - 384; }
    else              { src = bv; jj = j - 768; }
    bqkv[idx] = src[l * E + jj];
}

// ---------------- embedding + positional -> bf16 residual ----------------
__global__ void k_embed(const int* __restrict__ tokens, const float* __restrict__ pos,
                        const float* __restrict__ emb, bf16* __restrict__ x) {
    long idx = (long)blockIdx.x * 256 + threadIdx.x;
    int e = (int)(idx % E);
    long bt = idx / E;
    int t = (int)(bt % T);
    int tok = tokens[bt];
    x[idx] = (bf16)(emb[(long)tok * E + e] + pos[(long)t * E + e]);
}

// ---------------- launcher ----------------
extern "C" void kernel_launch(void* const* d_in, const int* in_sizes, int n_in,
                              void* d_out, int out_size, void* d_ws, size_t ws_size,
                              hipStream_t stream) {
    const int*   tokens = (const int*)d_in[0];
    const float* pos  = (const float*)d_in[1];
    const float* emb  = (const float*)d_in[2];
    const float* Wq   = (const float*)d_in[3];
    const float* bq   = (const float*)d_in[4];
    const float* Wk   = (const float*)d_in[5];
    const float* bk   = (const float*)d_in[6];
    const float* Wv   = (const float*)d_in[7];
    const float* bv   = (const float*)d_in[8];
    const float* Wo   = (const float*)d_in[9];
    const float* bo   = (const float*)d_in[10];
    const float* g1   = (const float*)d_in[11];
    const float* be1  = (const float*)d_in[12];
    const float* W1   = (const float*)d_in[13];
    const float* c1   = (const float*)d_in[14];
    const float* W2   = (const float*)d_in[15];
    const float* c2   = (const float*)d_in[16];
    const float* g2   = (const float*)d_in[17];
    const float* be2  = (const float*)d_in[18];
    const float* Wl   = (const float*)d_in[19];
    const float* bl   = (const float*)d_in[20];

    // ---- workspace layout (~173 MB peak) ----
    char* p = (char*)d_ws;
    bf16* x  = (bf16*)p;   p += (long)MTOT * E * 2;          // residual (bf16)
    bf16* h  = (bf16*)p;   p += (long)MTOT * E * 2;          // LN out / o (alias)
    bf16* qk = (bf16*)p;   p += (long)MTOT * 768 * 2;        // fused Q|K
    bf16* vt = (bf16*)p;   p += (long)BB * E * T * 2;        // V^T per (seq,head)
    bf16* SP = (bf16*)p;   p += (long)CB * NH * T * T * 2;   // kept only for mid alias span
    bf16* WqkvF = (bf16*)p; p += (long)NL * 1152 * E * 2;    // fragment layouts
    bf16* WoF = (bf16*)p;  p += (long)NL * E * E * 2;
    bf16* W1F = (bf16*)p;  p += (long)NL * DFF * E * 2;
    bf16* W2F = (bf16*)p;  p += (long)NL * E * DFF * 2;
    bf16* WlF = (bf16*)p;  p += (long)128 * E * 2;
    float* bqkv = (float*)p; p += (long)NL * 1152 * 4;
    bf16* mid = qk;          // alias: qk+vt+SP = 100.66 MB = MTOT*DFF*2 exactly
    bf16* o   = h;
    (void)SP;

    // ---- setup (once per call) ----
    k_transpose_qkv_frag<<<(NL * 1152 * E) / 256, 256, 0, stream>>>(Wq, Wk, Wv, WqkvF);
    k_transpose_frag<<<(NL * E * E) / 256, 256, 0, stream>>>(Wo, WoF, E, E, E);
    k_transpose_frag<<<(NL * DFF * E) / 256, 256, 0, stream>>>(W1, W1F, E, DFF, DFF);
    k_transpose_frag<<<(NL * E * DFF) / 256, 256, 0, stream>>>(W2, W2F, DFF, E, E);
    k_transpose_frag<<<(128 * E) / 256, 256, 0, stream>>>(Wl, WlF, E, NV, 128);
    k_bias_qkv<<<(NL * 1152) / 256, 256, 0, stream>>>(bq, bk, bv, bqkv);

    // ---- embedding ----
    k_embed<<<(MTOT * E) / 256, 256, 0, stream>>>(tokens, pos, emb, x);

    for (int l = 0; l < NL; l++) {
        // LN1
        k_ln<<<MTOT / 4, 256, 0, stream>>>(x, g1 + l * E, be1 + l * E, h);
        // fused QKV: M=32768, N=1152, K=384
        k_gemm<5><<<256 * 9, 512, 0, stream>>>(h, E, WqkvF + (long)l * 1152 * E,
                                               bqkv + l * 1152, qk, vt, 0,
                                               256, 9, 1152, E, 0);
        // fused causal attention
        k_attn<<<BB * NH * 4, 256, 0, stream>>>(qk, vt, o);
        // x += O @ Wo + bo
        k_gemm<1><<<256 * 3, 512, 0, stream>>>(o, E, WoF + (long)l * E * E,
                                               bo + l * E, x, nullptr, E,
                                               256, 3, E, E, 0);
        // LN2
        k_ln<<<MTOT / 4, 256, 0, stream>>>(x, g2 + l * E, be2 + l * E, h);
        // mid = relu(h @ W1 + c1)
        k_gemm<0><<<256 * 12, 512, 0, stream>>>(h, E, W1F + (long)l * DFF * E,
                                                c1 + l * DFF, mid, nullptr, DFF,
                                                256, 12, DFF, E, 1);
        // x += mid @ W2 + c2
        k_gemm<1><<<256 * 3, 512, 0, stream>>>(mid, DFF, W2F + (long)l * E * DFF,
                                               c2 + l * E, x, nullptr, E,
                                               256, 3, E, DFF, 0);
    }

    // logits = x @ Wl + bl  (N=65 masked from 128), f32 out
    k_gemm<4><<<256 * 1, 512, 0, stream>>>(x, E, WlF,
                                           bl, d_out, nullptr, NV,
                                           256, 1, NV, E, 0);
}